// Round 1
// baseline (409.379 us; speedup 1.0000x reference)
//
#include <hip/hip_runtime.h>
#include <math.h>

#define D_MODEL 512
#define NHEADS  8
#define DH      64
#define HIDDEN_ 2048
#define BB      2
#define NN      1024
#define MTOK    (BB*NN)

// ---------------- LayerNorm (row per block) ----------------
__global__ __launch_bounds__(256) void ln_kernel(const float* __restrict__ x,
    const float* __restrict__ g, const float* __restrict__ bta, float* __restrict__ y)
{
    int row = blockIdx.x;
    const float* xr = x + (size_t)row * D_MODEL;
    float* yr = y + (size_t)row * D_MODEL;
    int t = threadIdx.x;
    float2 v = *reinterpret_cast<const float2*>(&xr[t*2]);
    float s  = v.x + v.y;
    float ss = v.x*v.x + v.y*v.y;
    #pragma unroll
    for (int m = 1; m < 64; m <<= 1) { s += __shfl_xor(s, m); ss += __shfl_xor(ss, m); }
    __shared__ float red[8];
    int wid = t >> 6, lane = t & 63;
    if (lane == 0) { red[wid] = s; red[4+wid] = ss; }
    __syncthreads();
    s  = red[0] + red[1] + red[2] + red[3];
    ss = red[4] + red[5] + red[6] + red[7];
    float mu  = s * (1.0f / D_MODEL);
    float var = ss * (1.0f / D_MODEL) - mu * mu;
    float rs  = rsqrtf(var + 1e-5f);
    float2 gg = *reinterpret_cast<const float2*>(&g[t*2]);
    float2 bb = *reinterpret_cast<const float2*>(&bta[t*2]);
    float2 o;
    o.x = (v.x - mu) * rs * gg.x + bb.x;
    o.y = (v.y - mu) * rs * gg.y + bb.y;
    *reinterpret_cast<float2*>(&yr[t*2]) = o;
}

// ---------------- generic fp32 GEMM: C = A(MxK) @ B(KxN) + bias [+res] [gelu] ----
// EPI: 0 = bias only; 1 = bias + residual; 2 = bias + exact gelu
template<int EPI>
__global__ __launch_bounds__(256) void gemm_f32(
    const float* __restrict__ A, const float* __restrict__ Bm,
    const float* __restrict__ bias, const float* __restrict__ res,
    float* __restrict__ C, int M, int N, int K)
{
    __shared__ float As[16][64];
    __shared__ float Bs[16][64];
    int tid = threadIdx.x;
    int tx = tid & 15, ty = tid >> 4;
    int bm0 = blockIdx.y * 64, bn0 = blockIdx.x * 64;
    float acc[4][4] = {};
    int ar = tid >> 2, ak = (tid & 3) * 4;
    int bk = tid >> 4, bn = (tid & 15) * 4;

    for (int k0 = 0; k0 < K; k0 += 16) {
        float4 a4 = *reinterpret_cast<const float4*>(&A[(size_t)(bm0 + ar) * K + k0 + ak]);
        float4 b4 = *reinterpret_cast<const float4*>(&Bm[(size_t)(k0 + bk) * N + bn0 + bn]);
        As[ak+0][ar] = a4.x; As[ak+1][ar] = a4.y; As[ak+2][ar] = a4.z; As[ak+3][ar] = a4.w;
        *reinterpret_cast<float4*>(&Bs[bk][bn]) = b4;
        __syncthreads();
        #pragma unroll
        for (int k = 0; k < 16; ++k) {
            float4 av = *reinterpret_cast<const float4*>(&As[k][ty*4]);
            float4 bv = *reinterpret_cast<const float4*>(&Bs[k][tx*4]);
            const float aa[4] = {av.x, av.y, av.z, av.w};
            const float bb2[4] = {bv.x, bv.y, bv.z, bv.w};
            #pragma unroll
            for (int i = 0; i < 4; ++i)
                #pragma unroll
                for (int j = 0; j < 4; ++j)
                    acc[i][j] = fmaf(aa[i], bb2[j], acc[i][j]);
        }
        __syncthreads();
    }

    #pragma unroll
    for (int i = 0; i < 4; ++i) {
        int r  = bm0 + ty*4 + i;
        int c0 = bn0 + tx*4;
        float4 ov;
        float* po = &ov.x;
        #pragma unroll
        for (int j = 0; j < 4; ++j) {
            float v = acc[i][j] + bias[c0 + j];
            if (EPI == 2) v = 0.5f * v * (1.0f + erff(v * 0.70710678118654752f));
            po[j] = v;
        }
        if (EPI == 1) {
            float4 rv = *reinterpret_cast<const float4*>(&res[(size_t)r * N + c0]);
            ov.x += rv.x; ov.y += rv.y; ov.z += rv.z; ov.w += rv.w;
        }
        *reinterpret_cast<float4*>(&C[(size_t)r * N + c0]) = ov;
    }
}

// ---------------- fused attention (flash-style, 64-row Q tile per block) -------
// bias[b,h,i,j] = |coords[b,i]-coords[b,j]| * w_edge[2,h]   (frame averaging collapses)
__global__ __launch_bounds__(256) void attn_kernel(
    const float* __restrict__ qkv, const float* __restrict__ coords,
    const unsigned char* __restrict__ mask, const float* __restrict__ w_edge,
    float* __restrict__ o)
{
    int qt = blockIdx.x;   // 0..15  (q tile)
    int h  = blockIdx.y;   // 0..7
    int b  = blockIdx.z;   // 0..1
    int tid = threadIdx.x;
    int tx = tid & 15, ty = tid >> 4;
    int lane = tid & 63;

    __shared__ float QsT[64][68];   // [c][r], padded
    __shared__ float KsT[64][68];   // [c][j], padded
    __shared__ float Vs[64][64];    // [j][c]
    __shared__ float qcx[64], qcy[64], kcx[64], kcy[64];

    const float scale = 0.125f;                 // 64^-0.5
    const float we2   = w_edge[2*NHEADS + h];   // w_edge[2][h]

    // load Q tile transposed (scale folded in)
    #pragma unroll
    for (int it = 0; it < 4; ++it) {
        int idx = tid + it*256;
        int r = idx >> 4, cc = (idx & 15) * 4;
        int n = qt*64 + r;
        float4 v = *reinterpret_cast<const float4*>(&qkv[(size_t)(b*NN + n)*1536 + h*64 + cc]);
        QsT[cc+0][r] = v.x*scale; QsT[cc+1][r] = v.y*scale;
        QsT[cc+2][r] = v.z*scale; QsT[cc+3][r] = v.w*scale;
    }
    if (tid < 64) {
        qcx[tid] = coords[(size_t)(b*NN + qt*64 + tid)*2 + 0];
        qcy[tid] = coords[(size_t)(b*NN + qt*64 + tid)*2 + 1];
    }

    float m_i[4], l_i[4], acc[4][4];
    #pragma unroll
    for (int i = 0; i < 4; ++i) {
        m_i[i] = -1e30f; l_i[i] = 0.0f;
        #pragma unroll
        for (int j = 0; j < 4; ++j) acc[i][j] = 0.0f;
    }

    for (int jt = 0; jt < NN/64; ++jt) {
        __syncthreads();   // protect K/V LDS reuse from previous iteration
        #pragma unroll
        for (int it = 0; it < 4; ++it) {
            int idx = tid + it*256;
            int r = idx >> 4, cc = (idx & 15) * 4;
            int n = jt*64 + r;
            const float* kp = &qkv[(size_t)(b*NN + n)*1536 + 512 + h*64 + cc];
            float4 kv = *reinterpret_cast<const float4*>(kp);
            KsT[cc+0][r] = kv.x; KsT[cc+1][r] = kv.y; KsT[cc+2][r] = kv.z; KsT[cc+3][r] = kv.w;
            float4 vv = *reinterpret_cast<const float4*>(kp + 512);
            *reinterpret_cast<float4*>(&Vs[r][cc]) = vv;
        }
        if (tid < 64) {
            kcx[tid] = coords[(size_t)(b*NN + jt*64 + tid)*2 + 0];
            kcy[tid] = coords[(size_t)(b*NN + jt*64 + tid)*2 + 1];
        }
        __syncthreads();

        // S = Qs @ Ks^T  (4x4 per thread; rows ty*4+i, cols tx*4+j)
        float S[4][4] = {};
        #pragma unroll
        for (int k = 0; k < 64; ++k) {
            float4 qa = *reinterpret_cast<const float4*>(&QsT[k][ty*4]);
            float4 kb = *reinterpret_cast<const float4*>(&KsT[k][tx*4]);
            const float aa[4]  = {qa.x, qa.y, qa.z, qa.w};
            const float bb2[4] = {kb.x, kb.y, kb.z, kb.w};
            #pragma unroll
            for (int i = 0; i < 4; ++i)
                #pragma unroll
                for (int j = 0; j < 4; ++j)
                    S[i][j] = fmaf(aa[i], bb2[j], S[i][j]);
        }

        // radial bias + padding mask
        #pragma unroll
        for (int i = 0; i < 4; ++i) {
            int r = ty*4 + i;
            float qx = qcx[r], qy = qcy[r];
            size_t grow = (size_t)(b*NN + qt*64 + r);
            uchar4 mk = *reinterpret_cast<const uchar4*>(&mask[grow*NN + jt*64 + tx*4]);
            const unsigned char mks[4] = {mk.x, mk.y, mk.z, mk.w};
            #pragma unroll
            for (int j = 0; j < 4; ++j) {
                int c = tx*4 + j;
                float dx = qx - kcx[c], dy = qy - kcy[c];
                float rn = sqrtf(dx*dx + dy*dy);
                float v = S[i][j] + rn * we2;
                S[i][j] = mks[j] ? -1e9f : v;
            }
        }

        // online softmax update (row reductions over the 16 tx lanes)
        #pragma unroll
        for (int i = 0; i < 4; ++i) {
            float mx = fmaxf(fmaxf(S[i][0], S[i][1]), fmaxf(S[i][2], S[i][3]));
            #pragma unroll
            for (int m = 1; m < 16; m <<= 1) mx = fmaxf(mx, __shfl_xor(mx, m));
            float mnew = fmaxf(m_i[i], mx);
            float f = expf(m_i[i] - mnew);
            float rs = 0.0f;
            #pragma unroll
            for (int j = 0; j < 4; ++j) { S[i][j] = expf(S[i][j] - mnew); rs += S[i][j]; }
            #pragma unroll
            for (int m = 1; m < 16; m <<= 1) rs += __shfl_xor(rs, m);
            l_i[i] = l_i[i] * f + rs;
            m_i[i] = mnew;
            #pragma unroll
            for (int j = 0; j < 4; ++j) acc[i][j] *= f;
        }

        // PV: acc[i][jc] += sum_jj P[row_i][jj] * Vs[jj][tx*4+jc]
        // P rows are spread across the 16 tx lanes of the same ty group -> __shfl
        #pragma unroll
        for (int js = 0; js < 16; ++js) {
            #pragma unroll
            for (int jr = 0; jr < 4; ++jr) {
                int jj = js*4 + jr;
                float4 vv = *reinterpret_cast<const float4*>(&Vs[jj][tx*4]);
                int src = (lane & 48) + js;
                float p0 = __shfl(S[0][jr], src);
                float p1 = __shfl(S[1][jr], src);
                float p2 = __shfl(S[2][jr], src);
                float p3 = __shfl(S[3][jr], src);
                acc[0][0] = fmaf(p0, vv.x, acc[0][0]);
                acc[0][1] = fmaf(p0, vv.y, acc[0][1]);
                acc[0][2] = fmaf(p0, vv.z, acc[0][2]);
                acc[0][3] = fmaf(p0, vv.w, acc[0][3]);
                acc[1][0] = fmaf(p1, vv.x, acc[1][0]);
                acc[1][1] = fmaf(p1, vv.y, acc[1][1]);
                acc[1][2] = fmaf(p1, vv.z, acc[1][2]);
                acc[1][3] = fmaf(p1, vv.w, acc[1][3]);
                acc[2][0] = fmaf(p2, vv.x, acc[2][0]);
                acc[2][1] = fmaf(p2, vv.y, acc[2][1]);
                acc[2][2] = fmaf(p2, vv.z, acc[2][2]);
                acc[2][3] = fmaf(p2, vv.w, acc[2][3]);
                acc[3][0] = fmaf(p3, vv.x, acc[3][0]);
                acc[3][1] = fmaf(p3, vv.y, acc[3][1]);
                acc[3][2] = fmaf(p3, vv.z, acc[3][2]);
                acc[3][3] = fmaf(p3, vv.w, acc[3][3]);
            }
        }
    }

    // write O in (b, n, h*64 + c) layout (M x 512)
    #pragma unroll
    for (int i = 0; i < 4; ++i) {
        int n = qt*64 + ty*4 + i;
        float inv = 1.0f / l_i[i];
        float4 ov = {acc[i][0]*inv, acc[i][1]*inv, acc[i][2]*inv, acc[i][3]*inv};
        *reinterpret_cast<float4*>(&o[(size_t)(b*NN + n)*D_MODEL + h*64 + tx*4]) = ov;
    }
}

// -------------------------------------------------------------------------------
extern "C" void kernel_launch(void* const* d_in, const int* in_sizes, int n_in,
                              void* d_out, int out_size, void* d_ws, size_t ws_size,
                              hipStream_t stream)
{
    const float* x      = (const float*)d_in[0];
    const float* coords = (const float*)d_in[1];
    const unsigned char* mask = (const unsigned char*)d_in[2];
    const float* ln1_g = (const float*)d_in[3];
    const float* ln1_b = (const float*)d_in[4];
    const float* w_qkv = (const float*)d_in[5];
    const float* b_qkv = (const float*)d_in[6];
    const float* w_edge= (const float*)d_in[7];
    const float* w_out = (const float*)d_in[8];
    const float* b_out = (const float*)d_in[9];
    const float* ln2_g = (const float*)d_in[10];
    const float* ln2_b = (const float*)d_in[11];
    const float* w1    = (const float*)d_in[12];
    const float* b1    = (const float*)d_in[13];
    const float* w2    = (const float*)d_in[14];
    const float* b2    = (const float*)d_in[15];
    float* out = (float*)d_out;

    float* ws   = (float*)d_ws;
    float* xln  = ws;                  // 1,048,576 floats (reused as y later)
    float* qkvb = ws + 1048576;        // 3,145,728 floats
    float* ob   = ws + 4194304;        // 1,048,576 floats
    float* x1   = ws + 5242880;        // 1,048,576 floats
    float* y    = xln;                 // reuse (xln dead after qkv GEMM)
    float* hid  = qkvb;                // 4,194,304 floats, spans qkv+o (both dead)

    ln_kernel<<<MTOK, 256, 0, stream>>>(x, ln1_g, ln1_b, xln);
    gemm_f32<0><<<dim3(1536/64, MTOK/64), 256, 0, stream>>>(xln, w_qkv, b_qkv, nullptr, qkvb, MTOK, 1536, 512);
    attn_kernel<<<dim3(16, 8, 2), 256, 0, stream>>>(qkvb, coords, mask, w_edge, ob);
    gemm_f32<1><<<dim3(512/64, MTOK/64), 256, 0, stream>>>(ob, w_out, b_out, x, x1, MTOK, 512, 512);
    ln_kernel<<<MTOK, 256, 0, stream>>>(x1, ln2_g, ln2_b, y);
    gemm_f32<2><<<dim3(2048/64, MTOK/64), 256, 0, stream>>>(y, w1, b1, nullptr, hid, MTOK, 2048, 512);
    gemm_f32<1><<<dim3(512/64, MTOK/64), 256, 0, stream>>>(hid, w2, b2, x1, out, MTOK, 512, 2048);
}

// Round 2
// 134.453 us; speedup vs baseline: 3.0448x; 3.0448x over previous
//
#include <hip/hip_runtime.h>
#include <hip/hip_bf16.h>
#include <math.h>

#define NHEADS 8
#define NTOK   1024
#define MTOK   2048

typedef __attribute__((ext_vector_type(8))) short  sh8;
typedef __attribute__((ext_vector_type(8))) __bf16 bf16x8;
typedef __attribute__((ext_vector_type(4))) float  f32x4;

__device__ __forceinline__ short f2bf(float v) {
    return __builtin_bit_cast(short, __float2bfloat16(v));
}
__device__ __forceinline__ f32x4 mfma16(sh8 a, sh8 b, f32x4 c) {
    return __builtin_amdgcn_mfma_f32_16x16x32_bf16(
        __builtin_bit_cast(bf16x8, a), __builtin_bit_cast(bf16x8, b), c, 0, 0, 0);
}
__device__ __forceinline__ void aload16(void* lds, const void* g) {
    __builtin_amdgcn_global_load_lds(
        (const __attribute__((address_space(1))) unsigned int*)g,
        (__attribute__((address_space(3))) unsigned int*)lds, 16, 0, 0);
}

// ---------------- LayerNorm -> bf16 ----------------
__global__ __launch_bounds__(256) void ln_bf16(const float* __restrict__ x,
    const float* __restrict__ g, const float* __restrict__ bta, short* __restrict__ y)
{
    int row = blockIdx.x, t = threadIdx.x;
    const float* xr = x + (size_t)row * 512;
    float2 v = *reinterpret_cast<const float2*>(&xr[t*2]);
    float s = v.x + v.y, ss = v.x*v.x + v.y*v.y;
    #pragma unroll
    for (int m = 1; m < 64; m <<= 1) { s += __shfl_xor(s, m); ss += __shfl_xor(ss, m); }
    __shared__ float red[8];
    int wid = t >> 6, lane = t & 63;
    if (!lane) { red[wid] = s; red[4+wid] = ss; }
    __syncthreads();
    s = red[0]+red[1]+red[2]+red[3]; ss = red[4]+red[5]+red[6]+red[7];
    float mu = s*(1.f/512), var = ss*(1.f/512) - mu*mu, rs = rsqrtf(var + 1e-5f);
    float2 gg = *reinterpret_cast<const float2*>(&g[t*2]);
    float2 bb = *reinterpret_cast<const float2*>(&bta[t*2]);
    short2 o; o.x = f2bf((v.x-mu)*rs*gg.x + bb.x); o.y = f2bf((v.y-mu)*rs*gg.y + bb.y);
    *reinterpret_cast<short2*>(&y[(size_t)row*512 + t*2]) = o;
}

// ---------------- fp32 W[K][N] -> bf16 W^T[N][K] ----------------
__global__ __launch_bounds__(256) void wconv_t(const float* __restrict__ W,
    short* __restrict__ WT, int K, int N)
{
    __shared__ float t[32][33];
    int bn = blockIdx.x * 32, bk = blockIdx.y * 32;
    int c = threadIdx.x & 31, r8 = threadIdx.x >> 5;
    #pragma unroll
    for (int i = 0; i < 4; ++i) {
        int r = r8 + i*8;
        t[r][c] = W[(size_t)(bk + r)*N + bn + c];
    }
    __syncthreads();
    #pragma unroll
    for (int i = 0; i < 4; ++i) {
        int r = r8 + i*8;
        WT[(size_t)(bn + r)*K + bk + c] = f2bf(t[c][r]);
    }
}

// ---------------- bf16 MFMA GEMM: C[M][N] = A[M][K] @ BT[N][K]^T ----------------
// EPI: 0 bias; 1 bias+res(f32); 2 bias+gelu.  OUTBF: bf16 vs f32 output.
// BIAS_ROW: bias indexed by row (for the V^T GEMM).
template<int BM, int EPI, bool OUTBF, bool BIAS_ROW>
__global__ __launch_bounds__(256) void gemm_bf16(
    const short* __restrict__ A, const short* __restrict__ BT,
    const float* __restrict__ bias, const float* __restrict__ res,
    void* __restrict__ Cout, int M, int N, int K)
{
    constexpr int FM = BM / 32;          // frags per wave per dim
    constexpr int SLOTS = BM * 4;        // 16B slots per LDS tile
    __shared__ sh8 As8[SLOTS];
    __shared__ sh8 Bs8[SLOTS];
    int tid = threadIdx.x;
    int w = tid >> 6, lane = tid & 63, lr = lane & 15, lg = lane >> 4;
    int wr = w >> 1, wc = w & 1;
    int bm0 = blockIdx.y * BM, bn0 = blockIdx.x * BM;

    f32x4 zero = {0.f, 0.f, 0.f, 0.f};
    f32x4 acc[FM][FM];
    #pragma unroll
    for (int m = 0; m < FM; ++m)
        #pragma unroll
        for (int n = 0; n < FM; ++n) acc[m][n] = zero;

    for (int k0 = 0; k0 < K; k0 += 32) {
        __syncthreads();
        #pragma unroll
        for (int it = 0; it < SLOTS/256; ++it) {
            int s = tid + it*256;
            int r = s >> 2, g = s & 3;
            int ksw = k0 + ((g ^ (r & 3)) << 3);
            aload16(As8 + s, A  + (size_t)(bm0 + r)*K + ksw);
            aload16(Bs8 + s, BT + (size_t)(bn0 + r)*K + ksw);
        }
        asm volatile("s_waitcnt vmcnt(0)" ::: "memory");
        __syncthreads();

        sh8 af[FM], bfr[FM];
        #pragma unroll
        for (int m = 0; m < FM; ++m) {
            int R = wr*(BM/2) + m*16 + lr;
            af[m] = As8[R*4 + (lg ^ (R & 3))];
        }
        #pragma unroll
        for (int n = 0; n < FM; ++n) {
            int R = wc*(BM/2) + n*16 + lr;
            bfr[n] = Bs8[R*4 + (lg ^ (R & 3))];
        }
        #pragma unroll
        for (int m = 0; m < FM; ++m)
            #pragma unroll
            for (int n = 0; n < FM; ++n)
                acc[m][n] = mfma16(af[m], bfr[n], acc[m][n]);
    }

    // epilogue: C row = bm0 + wr*(BM/2) + m*16 + lg*4 + r; col = bn0 + wc*(BM/2) + n*16 + lr
    #pragma unroll
    for (int m = 0; m < FM; ++m) {
        #pragma unroll
        for (int n = 0; n < FM; ++n) {
            #pragma unroll
            for (int r = 0; r < 4; ++r) {
                int row = bm0 + wr*(BM/2) + m*16 + lg*4 + r;
                int col = bn0 + wc*(BM/2) + n*16 + lr;
                float v = acc[m][n][r] + (BIAS_ROW ? bias[row] : bias[col]);
                if (EPI == 2) v = 0.5f * v * (1.0f + erff(v * 0.70710678f));
                if (EPI == 1) v += res[(size_t)row*N + col];
                if (OUTBF) ((short*)Cout)[(size_t)row*N + col] = f2bf(v);
                else       ((float*)Cout)[(size_t)row*N + col] = v;
            }
        }
    }
}

// ---------------- MFMA flash attention ----------------
// qk: [2048 tok][1024] bf16 (q: h*64+d, k: 512+h*64+d);  vt: [512 vd][2048 tok] bf16
__global__ __launch_bounds__(256) void attn_mfma(
    const short* __restrict__ qk, const short* __restrict__ vt,
    const float* __restrict__ coords, const unsigned char* __restrict__ mask,
    const float* __restrict__ w_edge, short* __restrict__ o)
{
    int qt = blockIdx.x, h = blockIdx.y, b = blockIdx.z;
    int tid = threadIdx.x, w = tid >> 6, lane = tid & 63, lr = lane & 15, lg = lane >> 4;

    __shared__ sh8 Ks8[512];    // [64 k][64 d] swizzled (8 groups/row)
    __shared__ sh8 Vts8[512];   // [64 d][64 k] swizzled
    __shared__ sh8 Ps8[512];    // 4 waves x [16 q][64 k] swizzled
    __shared__ __attribute__((aligned(16))) unsigned char Msk[4096];  // [64 q][64 k]

    // Q fragments in registers: A operand row = lr (wave-local q), d = s*32 + lg*8..+7
    int qrow_g = b*NTOK + qt*64 + w*16 + lr;
    sh8 qf[2];
    #pragma unroll
    for (int s = 0; s < 2; ++s)
        qf[s] = *reinterpret_cast<const sh8*>(qk + (size_t)qrow_g*1024 + h*64 + s*32 + lg*8);

    // q coords for softmax rows (q = w*16 + lg*4 + r)
    float qx[4], qy[4];
    #pragma unroll
    for (int r = 0; r < 4; ++r) {
        int qr = b*NTOK + qt*64 + w*16 + lg*4 + r;
        float2 c = *reinterpret_cast<const float2*>(&coords[(size_t)qr*2]);
        qx[r] = c.x; qy[r] = c.y;
    }
    float we2 = w_edge[2*NHEADS + h];

    float m_i[4], l_i[4];
    f32x4 zero = {0.f,0.f,0.f,0.f};
    f32x4 accO[4];
    #pragma unroll
    for (int r = 0; r < 4; ++r) { m_i[r] = -1e30f; l_i[r] = 0.f; }
    #pragma unroll
    for (int n = 0; n < 4; ++n) accO[n] = zero;

    for (int jt = 0; jt < NTOK/64; ++jt) {
        __syncthreads();
        #pragma unroll
        for (int it = 0; it < 2; ++it) {
            int s = tid + it*256;
            int r = s >> 3, g = s & 7;
            aload16(Ks8 + s, qk + (size_t)(b*NTOK + jt*64 + r)*1024 + 512 + h*64 + ((g ^ (r&7)) << 3));
            int d = r;
            aload16(Vts8 + s, vt + (size_t)(h*64 + d)*2048 + b*NTOK + jt*64 + ((g ^ (d&7)) << 3));
        }
        aload16(Msk + tid*16, mask + (size_t)(b*NTOK + qt*64 + (tid>>2))*NTOK + jt*64 + ((tid&3) << 4));
        asm volatile("s_waitcnt vmcnt(0)" ::: "memory");
        __syncthreads();

        // S = Q K^T : col tile n -> S[q = lg*4+r][k = n*16+lr]
        f32x4 Sv[4];
        #pragma unroll
        for (int n = 0; n < 4; ++n) {
            f32x4 c = zero;
            int kcol = n*16 + lr;
            #pragma unroll
            for (int s = 0; s < 2; ++s) {
                int dg = s*4 + lg;
                c = mfma16(qf[s], Ks8[kcol*8 + (dg ^ (kcol & 7))], c);
            }
            Sv[n] = c;
        }

        // scale + radial bias + mask
        #pragma unroll
        for (int n = 0; n < 4; ++n) {
            int kcg = b*NTOK + jt*64 + n*16 + lr;
            float2 kc = *reinterpret_cast<const float2*>(&coords[(size_t)kcg*2]);
            #pragma unroll
            for (int r = 0; r < 4; ++r) {
                float dx = qx[r] - kc.x, dy = qy[r] - kc.y;
                float rn = sqrtf(dx*dx + dy*dy);
                float sv = Sv[n][r]*0.125f + rn*we2;
                unsigned char mb = Msk[(w*16 + lg*4 + r)*64 + n*16 + lr];
                Sv[n][r] = mb ? -1e9f : sv;
            }
        }

        // online softmax per row (16 lanes per row group share lg)
        float fsc[4];
        #pragma unroll
        for (int r = 0; r < 4; ++r) {
            float mx = fmaxf(fmaxf(Sv[0][r], Sv[1][r]), fmaxf(Sv[2][r], Sv[3][r]));
            #pragma unroll
            for (int msk = 1; msk < 16; msk <<= 1) mx = fmaxf(mx, __shfl_xor(mx, msk));
            float mnew = fmaxf(m_i[r], mx);
            fsc[r] = __expf(m_i[r] - mnew);
            m_i[r] = mnew;
            float rs = 0.f;
            #pragma unroll
            for (int n = 0; n < 4; ++n) { float p = __expf(Sv[n][r] - mnew); Sv[n][r] = p; rs += p; }
            #pragma unroll
            for (int msk = 1; msk < 16; msk <<= 1) rs += __shfl_xor(rs, msk);
            l_i[r] = l_i[r]*fsc[r] + rs;
            #pragma unroll
            for (int n = 0; n < 4; ++n) accO[n][r] *= fsc[r];
        }

        // P -> wave-private LDS (bf16, swizzled for A-frag reads)
        short* Pw = (short*)(Ps8 + (size_t)w*128);
        #pragma unroll
        for (int r = 0; r < 4; ++r) {
            int q = lg*4 + r;
            #pragma unroll
            for (int n = 0; n < 4; ++n) {
                int k = n*16 + lr;
                Pw[q*64 + (((k>>3) ^ (q&7)) << 3) + (k&7)] = f2bf(Sv[n][r]);
            }
        }

        // PV: A = P (row q = lr, k = s*32+lg*8..), B = V[k][d] from Vt LDS
        sh8 pa[2];
        #pragma unroll
        for (int s = 0; s < 2; ++s)
            pa[s] = Ps8[w*128 + lr*8 + ((s*4 + lg) ^ (lr & 7))];
        #pragma unroll
        for (int n = 0; n < 4; ++n) {
            int dcol = n*16 + lr;
            #pragma unroll
            for (int s = 0; s < 2; ++s) {
                int kg = s*4 + lg;
                accO[n] = mfma16(pa[s], Vts8[dcol*8 + (kg ^ (dcol & 7))], accO[n]);
            }
        }
    }

    // O[q][h*64 + d] bf16
    #pragma unroll
    for (int r = 0; r < 4; ++r) {
        float inv = 1.0f / l_i[r];
        size_t qg = (size_t)(b*NTOK + qt*64 + w*16 + lg*4 + r);
        #pragma unroll
        for (int n = 0; n < 4; ++n)
            o[qg*512 + h*64 + n*16 + lr] = f2bf(accO[n][r] * inv);
    }
}

// -------------------------------------------------------------------------------
extern "C" void kernel_launch(void* const* d_in, const int* in_sizes, int n_in,
                              void* d_out, int out_size, void* d_ws, size_t ws_size,
                              hipStream_t stream)
{
    const float* x      = (const float*)d_in[0];
    const float* coords = (const float*)d_in[1];
    const unsigned char* mask = (const unsigned char*)d_in[2];
    const float* ln1_g = (const float*)d_in[3];
    const float* ln1_b = (const float*)d_in[4];
    const float* w_qkv = (const float*)d_in[5];
    const float* b_qkv = (const float*)d_in[6];
    const float* w_edge= (const float*)d_in[7];
    const float* w_out = (const float*)d_in[8];
    const float* b_out = (const float*)d_in[9];
    const float* ln2_g = (const float*)d_in[10];
    const float* ln2_b = (const float*)d_in[11];
    const float* w1    = (const float*)d_in[12];
    const float* b1    = (const float*)d_in[13];
    const float* w2    = (const float*)d_in[14];
    const float* b2    = (const float*)d_in[15];
    float* out = (float*)d_out;

    char* W = (char*)d_ws;
    const size_t MB = 1024*1024;
    // phase 1 layout
    float* x1     = (float*)(W + 0);        // [0,4M) f32 2048x512, live to end
    short* xln    = (short*)(W + 4*MB);     // [4M,6M) bf16 2048x512 (later: y)
    short* wqkvT  = (short*)(W + 6*MB);     // [6M,7.5M) bf16 1536x512
    short* woutT  = (short*)(W + 7*MB + 512*1024);  // [7.5M,8M) 512x512
    short* qk     = (short*)(W + 8*MB);     // [8M,12M) bf16 2048x1024
    short* vtb    = (short*)(W + 12*MB);    // [12M,14M) bf16 512x2048
    short* ob     = (short*)(W + 14*MB);    // [14M,16M) bf16 2048x512
    // phase 2 layout (over dead phase-1 regions)
    short* y      = xln;                    // [4M,6M)
    short* w1T    = (short*)(W + 6*MB);     // [6M,8M) 2048x512
    short* w2T    = (short*)(W + 8*MB);     // [8M,10M) 512x2048
    short* hid    = (short*)(W + 10*MB);    // [10M,18M) bf16 2048x2048

    // phase 1
    wconv_t<<<dim3(1536/32, 512/32), 256, 0, stream>>>(w_qkv, wqkvT, 512, 1536);
    wconv_t<<<dim3(512/32, 512/32), 256, 0, stream>>>(w_out, woutT, 512, 512);
    ln_bf16<<<MTOK, 256, 0, stream>>>(x, ln1_g, ln1_b, xln);
    // qk = xln @ w_qkv[:, :1024]
    gemm_bf16<64,0,true,false><<<dim3(1024/64, MTOK/64), 256, 0, stream>>>(
        xln, wqkvT, b_qkv, nullptr, qk, MTOK, 1024, 512);
    // vt = Wv^T @ xln^T   (rows = v-dim, cols = tokens)
    gemm_bf16<64,0,true,true><<<dim3(MTOK/64, 512/64), 256, 0, stream>>>(
        wqkvT + (size_t)1024*512, xln, b_qkv + 1024, nullptr, vtb, 512, MTOK, 512);
    attn_mfma<<<dim3(16, NHEADS, 2), 256, 0, stream>>>(qk, vtb, coords, mask, w_edge, ob);
    // x1 = ob @ w_out + b_out + x
    gemm_bf16<64,1,false,false><<<dim3(512/64, MTOK/64), 256, 0, stream>>>(
        ob, woutT, b_out, x, x1, MTOK, 512, 512);
    // phase 2
    wconv_t<<<dim3(2048/32, 512/32), 256, 0, stream>>>(w1, w1T, 512, 2048);
    wconv_t<<<dim3(512/32, 2048/32), 256, 0, stream>>>(w2, w2T, 2048, 512);
    ln_bf16<<<MTOK, 256, 0, stream>>>(x1, ln2_g, ln2_b, y);
    gemm_bf16<128,2,true,false><<<dim3(2048/128, MTOK/128), 256, 0, stream>>>(
        y, w1T, b1, nullptr, hid, MTOK, 2048, 512);
    gemm_bf16<64,1,false,false><<<dim3(512/64, MTOK/64), 256, 0, stream>>>(
        hid, w2T, b2, x1, out, MTOK, 512, 2048);
}